// Round 4
// baseline (135.587 us; speedup 1.0000x reference)
//
#include <hip/hip_runtime.h>
#include <stdint.h>

#define NN 16384
#define DD 128
#define KT 64        // k-tile rows
#define QB 128       // q rows per block (4 waves x 32)
#define KSTR 144     // K LDS row stride (128 data + 16 pad): 9 x 16B units/row
#define VSTR 72      // V^T LDS row stride (64 data + 8 pad)
#define KBYTES 9216  // 64 * 144
#define VBYTES 9216  // 128 * 72

typedef float f32x16 __attribute__((ext_vector_type(16)));
typedef long long i64;

using gv = __attribute__((address_space(1))) const void;
using lv = __attribute__((address_space(3))) void;

// K1: row L2-norms -> nx fp8 (e4m3), scaled by sqrt(log2(e)) so QK^T dots
// come out pre-multiplied by log2(e) -> softmax is a bare v_exp_f32 (2^x).
__global__ void k_norm(const float* __restrict__ x, uint8_t* __restrict__ nx) {
  const int wave = threadIdx.x >> 6, lane = threadIdx.x & 63;
  const int row = blockIdx.x * 4 + wave;
  const float2 v = *reinterpret_cast<const float2*>(x + (size_t)row * DD + 2 * lane);
  float ss = v.x * v.x + v.y * v.y;
#pragma unroll
  for (int m = 1; m < 64; m <<= 1) ss += __shfl_xor(ss, m);
  const float rn = 1.2011224087f / fmaxf(sqrtf(ss), 1e-12f);  // sqrt(log2 e)/|x|
  const int w = __builtin_amdgcn_cvt_pk_fp8_f32(v.x * rn, v.y * rn, 0, false);
  *reinterpret_cast<uint16_t*>(nx + (size_t)row * DD + 2 * lane) = (uint16_t)w;
}

// K1b: transpose x (fp32 [N][D]) -> xT (fp8 [D][N]) via LDS tile.
__global__ void k_transpose(const float* __restrict__ x, uint8_t* __restrict__ xT) {
  __shared__ uint16_t tile[64 * 66];  // 64 n-rows x 128 d fp8, row stride 132B
  const int n0 = blockIdx.x * 64;
  const int t = threadIdx.x;
#pragma unroll
  for (int e = 0; e < 16; ++e) {
    const int idx = e * 256 + t;
    const int r = idx >> 6, c2 = idx & 63;
    const float2 v = *reinterpret_cast<const float2*>(x + (size_t)(n0 + r) * DD + 2 * c2);
    const int w = __builtin_amdgcn_cvt_pk_fp8_f32(v.x, v.y, 0, false);
    tile[r * 66 + c2] = (uint16_t)w;
  }
  __syncthreads();
  const uint8_t* t8 = reinterpret_cast<const uint8_t*>(tile);
#pragma unroll
  for (int e = 0; e < 8; ++e) {
    const int idx = e * 256 + t;
    const int d = idx >> 4, n4 = (idx & 15) << 2;
    uint32_t w = (uint32_t)t8[(n4 + 0) * 132 + d];
    w |= (uint32_t)t8[(n4 + 1) * 132 + d] << 8;
    w |= (uint32_t)t8[(n4 + 2) * 132 + d] << 16;
    w |= (uint32_t)t8[(n4 + 3) * 132 + d] << 24;
    *reinterpret_cast<uint32_t*>(xT + (size_t)d * NN + n0 + n4) = w;
  }
}

// K2: flash attention, 4 waves x 32 q-rows, fp8 32x32x16 MFMA, swapped QK^T,
// in-register softmax, P packed to fp8 via cvt_pk_fp8 + permlane32_swap.
// Padded LDS strides (144/72) instead of XOR swizzle -> conflict-free b64
// reads. 2-buffer staging; per-wave vmcnt(0) BEFORE the barrier (producer
// publishes); waves 0,1 stage K units, waves 2,3 stage V units.
template <int NSPLIT>
__global__ __launch_bounds__(256, 4) void k_attn(
    const uint8_t* __restrict__ nx, const uint8_t* __restrict__ xT,
    float* __restrict__ Op, float* __restrict__ Lp) {
  __shared__ alignas(16) uint8_t Kb[2][KBYTES];
  __shared__ alignas(16) uint8_t Vb[2][VBYTES];

  const int tid = threadIdx.x;
  const int wave = tid >> 6;
  const int lane = tid & 63;
  const int rl = lane & 31;
  const int hi = lane >> 5;

  // XCD-grouped decomposition: split s occupies XCD group -> K/V L2-resident.
  const int id = blockIdx.x;
  constexpr int gs = 8 / NSPLIT;
  const int split = (id & 7) / gs;
  const int qblock = (id >> 3) * gs + (id & (gs - 1));

  constexpr int nt = (NN / KT) / NSPLIT;
  const int t0s = split * nt;
  const int qw = qblock * QB + wave * 32;

  // ---- staging precompute: waves 0,1 handle K (units 0-8); 2,3 handle V ----
  const int sw = wave >> 1;            // 0 = K-stager, 1 = V-stager
  const int j0 = (wave & 1) * 5;       // first unit
  const int cnt = (wave & 1) ? 4 : 5;  // units this wave stages per tile
  uint32_t soff[5];
#pragma unroll
  for (int i = 0; i < 5; ++i) {
    const int j = j0 + i;              // 1024B unit index 0..8
    const int t16 = j * 64 + lane;     // 16B sub-unit index
    if (sw == 0) {
      // K: LDS row stride 144 = 9 units; unit 9k+8 is pad (reads next row: ok)
      soff[i] = (uint32_t)((t16 / 9) * DD + (t16 % 9) * 16);
    } else {
      // V^T: LDS row stride 72; c0 in {0,8,...,64}; c0==64 straddles into d+1
      const int d = (2 * t16) / 9;
      const int c0 = t16 * 16 - d * VSTR;
      soff[i] = (uint32_t)(d * NN + c0 + (c0 >= 64 ? (NN - VSTR) : 0));
    }
  }

  auto stage = [&](int tt, int buf) {
    const int k0 = tt * KT;
    const uint8_t* basep = (sw == 0) ? (nx + (size_t)k0 * DD) : (xT + k0);
    uint8_t* ldsb = (sw == 0) ? &Kb[buf][0] : &Vb[buf][0];
#pragma unroll
    for (int i = 0; i < 5; ++i)
      if (i < cnt)
        __builtin_amdgcn_global_load_lds((gv*)(basep + soff[i]),
            (lv*)(ldsb + (j0 + i) * 1024), 16, 0, 0);
  };

  // Q B-frags (fp8): col q = l&31, d-elements dc*16 + 8*hi .. +8
  i64 q8[8];
#pragma unroll
  for (int dc = 0; dc < 8; ++dc)
    q8[dc] = *reinterpret_cast<const i64*>(nx + (size_t)(qw + rl) * DD + dc * 16 + 8 * hi);

  f32x16 o[4];
#pragma unroll
  for (int dt = 0; dt < 4; ++dt)
#pragma unroll
    for (int r = 0; r < 16; ++r) o[dt][r] = 0.f;
  float lsum = 0.f;

  stage(t0s, 0);

  for (int t = 0; t < nt; ++t) {
    const int buf = t & 1;
    __builtin_amdgcn_sched_barrier(0);
    asm volatile("s_waitcnt vmcnt(0)" ::: "memory");  // own stage(t) landed
    __builtin_amdgcn_sched_barrier(0);
    __builtin_amdgcn_s_barrier();                     // all stage(t) published
    __builtin_amdgcn_sched_barrier(0);
    if (t + 1 < nt) stage(t0s + t + 1, buf ^ 1);

    const uint8_t* kb = &Kb[buf][0];
    const uint8_t* vb = &Vb[buf][0];
    i64 pa[4];

    // ---- per 32-row k-subtile: QK^T then immediate softmax+pack ----
#pragma unroll
    for (int kt = 0; kt < 2; ++kt) {
      const uint8_t* kbb = kb + kt * 32 * KSTR;
      f32x16 s;
#pragma unroll
      for (int r = 0; r < 16; ++r) s[r] = 0.f;
      __builtin_amdgcn_s_setprio(1);
#pragma unroll
      for (int dc = 0; dc < 8; ++dc) {
        const i64 ka = __builtin_bit_cast(i64,
            *reinterpret_cast<const uint2*>(kbb + rl * KSTR + dc * 16 + 8 * hi));
        s = __builtin_amdgcn_mfma_f32_32x32x16_fp8_fp8(ka, q8[dc], s, 0, 0, 0);
      }
      __builtin_amdgcn_s_setprio(0);
      // softmax: p = 2^s (s pre-scaled by log2 e; |s|<=1.45, no max tracking)
      // lane holds P[q=l&31][k_local=(r&3)+8*(r>>2)+4*hi+32*kt]
#pragma unroll
      for (int kc = 0; kc < 2; ++kc) {
        float e[8];
#pragma unroll
        for (int j = 0; j < 8; ++j) {
          float p;
          asm("v_exp_f32 %0, %1" : "=v"(p) : "v"(s[8 * kc + j]));
          e[j] = p;
          lsum += p;
        }
        uint32_t wlo = (uint32_t)__builtin_amdgcn_cvt_pk_fp8_f32(e[0], e[1], 0, false);
        wlo = (uint32_t)__builtin_amdgcn_cvt_pk_fp8_f32(e[2], e[3], (int)wlo, true);
        uint32_t whi = (uint32_t)__builtin_amdgcn_cvt_pk_fp8_f32(e[4], e[5], 0, false);
        whi = (uint32_t)__builtin_amdgcn_cvt_pk_fp8_f32(e[6], e[7], (int)whi, true);
        asm("v_permlane32_swap_b32 %0, %1" : "+v"(wlo), "+v"(whi));
        const uint2 pd = {wlo, whi};
        pa[kt * 2 + kc] = __builtin_bit_cast(i64, pd);
      }
    }

    // ---- PV: O[q][d] += P * V ----
    __builtin_amdgcn_s_setprio(1);
#pragma unroll
    for (int c4 = 0; c4 < 4; ++c4) {
      const int cb = c4 * 16 + 8 * hi;
#pragma unroll
      for (int dt = 0; dt < 4; ++dt) {
        const i64 vf = __builtin_bit_cast(i64,
            *reinterpret_cast<const uint2*>(vb + (dt * 32 + rl) * VSTR + cb));
        o[dt] = __builtin_amdgcn_mfma_f32_32x32x16_fp8_fp8(pa[c4], vf, o[dt], 0, 0, 0);
      }
    }
    __builtin_amdgcn_s_setprio(0);
  }

  // L[q]: lanes l and l+32 hold complementary k-subsets of the same q
  const float lt = lsum + __shfl_xor(lsum, 32);
  if (hi == 0) Lp[(size_t)split * NN + qw + rl] = lt;

  float* Ob = Op + (size_t)split * NN * DD;
#pragma unroll
  for (int dt = 0; dt < 4; ++dt)
#pragma unroll
    for (int r = 0; r < 16; ++r) {
      const int q = (r & 3) + 8 * (r >> 2) + 4 * hi;
      Ob[(size_t)(qw + q) * DD + dt * 32 + rl] = o[dt][r];
    }
}

// K3: combine splits, y = 1.5x - 0.5*(O/L), LayerNorm over D, write fp32 out.
__global__ void k_final(const float* __restrict__ x, const float* __restrict__ gamma,
                        const float* __restrict__ beta, const float* __restrict__ Op,
                        const float* __restrict__ Lp, float* __restrict__ out, int nsplit) {
  const int wave = threadIdx.x >> 6, lane = threadIdx.x & 63;
  const int row = blockIdx.x * 4 + wave;
  float o0 = 0.f, o1 = 0.f, lt = 0.f;
  for (int s = 0; s < nsplit; ++s) {
    const float2 v = *reinterpret_cast<const float2*>(
        Op + (size_t)s * NN * DD + (size_t)row * DD + 2 * lane);
    o0 += v.x;
    o1 += v.y;
    lt += Lp[(size_t)s * NN + row];
  }
  const float inv = 1.0f / lt;
  const float2 xv = *reinterpret_cast<const float2*>(x + (size_t)row * DD + 2 * lane);
  float y0 = 1.5f * xv.x - 0.5f * o0 * inv;
  float y1 = 1.5f * xv.y - 0.5f * o1 * inv;
  float sum = y0 + y1;
#pragma unroll
  for (int m = 1; m < 64; m <<= 1) sum += __shfl_xor(sum, m);
  const float mu = sum * (1.0f / 128.0f);
  const float d0 = y0 - mu, d1 = y1 - mu;
  float vs = d0 * d0 + d1 * d1;
#pragma unroll
  for (int m = 1; m < 64; m <<= 1) vs += __shfl_xor(vs, m);
  const float rs = rsqrtf(vs * (1.0f / 128.0f) + 1e-5f);
  const float2 g = *reinterpret_cast<const float2*>(gamma + 2 * lane);
  const float2 b = *reinterpret_cast<const float2*>(beta + 2 * lane);
  float2 ov;
  ov.x = d0 * rs * g.x + b.x;
  ov.y = d1 * rs * g.y + b.y;
  *reinterpret_cast<float2*>(out + (size_t)row * DD + 2 * lane) = ov;
}

extern "C" void kernel_launch(void* const* d_in, const int* in_sizes, int n_in,
                              void* d_out, int out_size, void* d_ws, size_t ws_size,
                              hipStream_t stream) {
  const float* x = (const float*)d_in[0];
  const float* gamma = (const float*)d_in[1];
  const float* beta = (const float*)d_in[2];
  float* out = (float*)d_out;
  char* ws = (char*)d_ws;

  uint8_t* nx = (uint8_t*)ws;                           // 2 MiB fp8 [N][D], scaled
  uint8_t* xT = (uint8_t*)(ws + (size_t)NN * DD);       // 2 MiB fp8 [D][N]
  const size_t base = (size_t)2 * NN * DD;
  const size_t per = (size_t)NN * DD * 4 + (size_t)NN * 4;  // per-split O + L

  int nsplit = 2;
  if (ws_size >= base + 8 * per) nsplit = 8;
  else if (ws_size >= base + 4 * per) nsplit = 4;

  float* Op = (float*)(ws + base);
  float* Lp = (float*)(ws + base + (size_t)nsplit * NN * DD * 4);

  k_norm<<<NN / 4, 256, 0, stream>>>(x, nx);
  k_transpose<<<NN / 64, 256, 0, stream>>>(x, xT);
  if (nsplit == 8)
    k_attn<8><<<dim3((NN / QB) * 8), 256, 0, stream>>>(nx, xT, Op, Lp);
  else if (nsplit == 4)
    k_attn<4><<<dim3((NN / QB) * 4), 256, 0, stream>>>(nx, xT, Op, Lp);
  else
    k_attn<2><<<dim3((NN / QB) * 2), 256, 0, stream>>>(nx, xT, Op, Lp);
  k_final<<<NN / 4, 256, 0, stream>>>(x, gamma, beta, Op, Lp, out, nsplit);
}